// Round 1
// baseline (351.201 us; speedup 1.0000x reference)
//
#include <hip/hip_runtime.h>
#include <math.h>

#define BB 64
#define SS 2048
#define FF 1024
#define HH 1024
#define NCHUNK 16
#define CHUNK_S 128   // SS/NCHUNK
#define RPW 32        // rows per wave (CHUNK_S/4)
#define KS 4          // k-split for GRU GEMM
#define KC 256        // HH/KS

// ---- workspace layout (float offsets) ----
#define WS_BASE 0                     // 64
#define WS_PM   64                    // 1024
#define WS_PL   (64+1024)             // 1024
#define WS_MB   (64+2048)             // 64
#define WS_LB   (64+2048+64)          // 64
#define WS_BIG  2240                  // max(pacc 1048576, gpart 1572864)
#define WS_XT   (2240+1572864)        // 1025*64 = 65600
#define WS_HT   (WS_XT+65600)         // 65536
#define WS_X2T  (WS_HT+65536)         // 65536
#define WS_RHT  (WS_X2T+65536)        // 65536

__device__ __forceinline__ float sigm(float x){ return 1.f/(1.f + __expf(-x)); }

// ---------- A: transpose hidden -> hT[k][b], compute base[b] = h.w_h + input*w_i + attn_b ----------
__global__ __launch_bounds__(256) void kA(const float* __restrict__ h,
                                          const float* __restrict__ input,
                                          const float* __restrict__ attn_W,
                                          const float* __restrict__ attn_b,
                                          float* __restrict__ hT,
                                          float* __restrict__ base)
{
    int b = blockIdx.x;
    int tid = threadIdx.x;                 // 256
    const float4* h4  = (const float4*)(h + (size_t)b*HH);
    const float4* wh4 = (const float4*)(attn_W + FF);
    float4 hv = h4[tid];
    float4 wv = wh4[tid];
    int k = tid*4;
    hT[(k+0)*BB + b] = hv.x;
    hT[(k+1)*BB + b] = hv.y;
    hT[(k+2)*BB + b] = hv.z;
    hT[(k+3)*BB + b] = hv.w;
    float p = hv.x*wv.x + hv.y*wv.y + hv.z*wv.z + hv.w*wv.w;
    #pragma unroll
    for (int off=32; off; off>>=1) p += __shfl_xor(p, off);
    __shared__ float red[4];
    if ((tid&63)==0) red[tid>>6] = p;
    __syncthreads();
    if (tid==0){
        float dot = red[0]+red[1]+red[2]+red[3];
        float w_i = attn_W[FF+HH];
        base[b] = dot + input[b]*w_i + attn_b[0];
    }
}

// ---------- B: fused scores + online-softmax weighted accumulation ----------
__global__ __launch_bounds__(256) void kB(const float* __restrict__ enc,
                                          const int*   __restrict__ mask,
                                          const float* __restrict__ attn_W,
                                          const float* __restrict__ base,
                                          float* __restrict__ scores_out,   // d_out attn region (raw scores)
                                          float* __restrict__ pacc,        // (B*NCHUNK, F)
                                          float* __restrict__ pm,
                                          float* __restrict__ pl)
{
    const int tid  = threadIdx.x;
    const int lane = tid & 63;
    const int w    = tid >> 6;
    const int b    = blockIdx.x >> 4;      // /NCHUNK
    const int c    = blockIdx.x & 15;
    const int s0   = c*CHUNK_S + w*RPW;

    const float4* we4 = (const float4*)attn_W;
    const float4 we0 = we4[lane], we1 = we4[64+lane], we2 = we4[128+lane], we3 = we4[192+lane];

    float m = -INFINITY, l = 0.f;
    float4 a0 = make_float4(0,0,0,0), a1 = a0, a2 = a0, a3 = a0;
    const float bb = base[b];
    float sc_keep = 0.f;

    const float4* rowbase = (const float4*)(enc + (size_t)(b*SS + s0)*FF);
    const int* mrow = mask + b*SS + s0;

    for (int i=0;i<RPW;i++){
        const float4* row = rowbase + (size_t)i*(FF/4);
        float4 e0 = row[lane], e1 = row[64+lane], e2 = row[128+lane], e3 = row[192+lane];
        float dot = e0.x*we0.x + e0.y*we0.y + e0.z*we0.z + e0.w*we0.w
                  + e1.x*we1.x + e1.y*we1.y + e1.z*we1.z + e1.w*we1.w
                  + e2.x*we2.x + e2.y*we2.y + e2.z*we2.z + e2.w*we2.w
                  + e3.x*we3.x + e3.y*we3.y + e3.z*we3.z + e3.w*we3.w;
        #pragma unroll
        for (int off=32; off; off>>=1) dot += __shfl_xor(dot, off);
        float score = dot + bb;
        if (mrow[i] == 0) score = -1e10f;
        sc_keep = (lane == i) ? score : sc_keep;
        float newm  = fmaxf(m, score);
        float scale = __expf(m - newm);
        float p     = __expf(score - newm);
        l = l*scale + p;
        a0.x = a0.x*scale + p*e0.x; a0.y = a0.y*scale + p*e0.y; a0.z = a0.z*scale + p*e0.z; a0.w = a0.w*scale + p*e0.w;
        a1.x = a1.x*scale + p*e1.x; a1.y = a1.y*scale + p*e1.y; a1.z = a1.z*scale + p*e1.z; a1.w = a1.w*scale + p*e1.w;
        a2.x = a2.x*scale + p*e2.x; a2.y = a2.y*scale + p*e2.y; a2.z = a2.z*scale + p*e2.z; a2.w = a2.w*scale + p*e2.w;
        a3.x = a3.x*scale + p*e3.x; a3.y = a3.y*scale + p*e3.y; a3.z = a3.z*scale + p*e3.z; a3.w = a3.w*scale + p*e3.w;
        m = newm;
    }
    if (lane < RPW) scores_out[b*SS + s0 + lane] = sc_keep;

    __shared__ float sm[4], sl[4];
    __shared__ float4 sacc[4][256];
    if (lane==0) sm[w] = m;
    __syncthreads();
    float M = fmaxf(fmaxf(sm[0],sm[1]), fmaxf(sm[2],sm[3]));
    float scw = __expf(m - M);
    if (lane==0) sl[w] = l*scw;
    float4 t;
    t.x=a0.x*scw; t.y=a0.y*scw; t.z=a0.z*scw; t.w=a0.w*scw; sacc[w][lane]      = t;
    t.x=a1.x*scw; t.y=a1.y*scw; t.z=a1.z*scw; t.w=a1.w*scw; sacc[w][64+lane]   = t;
    t.x=a2.x*scw; t.y=a2.y*scw; t.z=a2.z*scw; t.w=a2.w*scw; sacc[w][128+lane]  = t;
    t.x=a3.x*scw; t.y=a3.y*scw; t.z=a3.z*scw; t.w=a3.w*scw; sacc[w][192+lane]  = t;
    __syncthreads();
    float4 tot = sacc[0][tid];
    #pragma unroll
    for (int q=1;q<4;q++){ float4 u = sacc[q][tid]; tot.x+=u.x; tot.y+=u.y; tot.z+=u.z; tot.w+=u.w; }
    ((float4*)(pacc + (size_t)blockIdx.x*FF))[tid] = tot;
    if (tid==0){
        pm[blockIdx.x] = M;
        pl[blockIdx.x] = sl[0]+sl[1]+sl[2]+sl[3];
    }
}

// ---------- C: merge chunk partials -> x_T (concat input + attn_applied, transposed), M/invL per b ----------
__global__ __launch_bounds__(256) void kC(const float* __restrict__ pacc,
                                          const float* __restrict__ pm,
                                          const float* __restrict__ pl,
                                          const float* __restrict__ input,
                                          float* __restrict__ xT,   // (1025, B)
                                          float* __restrict__ Mb,
                                          float* __restrict__ Lb)   // stores 1/L
{
    int b = blockIdx.x, tid = threadIdx.x;
    float M = -INFINITY;
    #pragma unroll
    for (int c=0;c<NCHUNK;c++) M = fmaxf(M, pm[b*NCHUNK+c]);
    float L = 0.f;
    float sc[NCHUNK];
    #pragma unroll
    for (int c=0;c<NCHUNK;c++){ sc[c] = __expf(pm[b*NCHUNK+c]-M); L += pl[b*NCHUNK+c]*sc[c]; }
    float invL = 1.f/L;
    #pragma unroll
    for (int q=0;q<4;q++){
        int f = q*256 + tid;
        float a = 0.f;
        #pragma unroll
        for (int c=0;c<NCHUNK;c++) a += pacc[((size_t)(b*NCHUNK+c))*FF + f]*sc[c];
        xT[(1+f)*BB + b] = a*invL;
    }
    if (tid==0){ xT[b] = input[b]; Mb[b]=M; Lb[b]=invL; }
}

// ---------- D: in-place scores -> softmax weights ----------
__global__ __launch_bounds__(256) void kD(float* __restrict__ wout,
                                          const float* __restrict__ Mb,
                                          const float* __restrict__ Lb)
{
    int idx = blockIdx.x*256 + threadIdx.x;   // B*S total
    int b = idx >> 11;                        // /S
    float s = wout[idx];
    wout[idx] = __expf(s - Mb[b]) * Lb[b];
}

// ---------- E: x2 = relu(x_in @ combine_W^T + combine_b), output transposed ----------
__global__ __launch_bounds__(256) void kE(const float* __restrict__ xT,   // (1025,B)
                                          const float* __restrict__ cW,   // (H, 1025)
                                          const float* __restrict__ cb,
                                          float* __restrict__ x2T)        // (H,B)
{
    int lane = threadIdx.x & 63, w = threadIdx.x >> 6;
    int j0 = blockIdx.x*8 + w*2;
    const float* w0 = cW + (size_t)j0*(FF+1);
    const float* w1 = w0 + (FF+1);
    float a0 = 0.f, a1 = 0.f;
    #pragma unroll 8
    for (int k=0;k<FF+1;k++){
        float x = xT[k*BB + lane];
        a0 += x*w0[k];
        a1 += x*w1[k];
    }
    a0 += cb[j0]; a1 += cb[j0+1];
    x2T[(size_t)j0*BB + lane]     = fmaxf(a0, 0.f);
    x2T[(size_t)(j0+1)*BB + lane] = fmaxf(a1, 0.f);
}

// ---------- F1: k-split partial GEMM for gi (x2) and gh (h), 6 gate rows per j ----------
__global__ __launch_bounds__(256) void kF1(const float* __restrict__ x2T,
                                           const float* __restrict__ hT,
                                           const float* __restrict__ W_ih,
                                           const float* __restrict__ W_hh,
                                           float* __restrict__ gpart)  // [(kc*6+g)*H + j]*B + b
{
    int lane = threadIdx.x & 63, w = threadIdx.x >> 6;
    int jb = blockIdx.x >> 2, kc = blockIdx.x & 3;
    int j0 = jb*16 + w*4;
    int k0 = kc*KC;
    float a[6][4];
    const float* pw[6][4];
    #pragma unroll
    for (int jj=0;jj<4;jj++){
        int j = j0+jj;
        pw[0][jj] = W_ih + (size_t)j*HH + k0;
        pw[1][jj] = W_ih + (size_t)(HH+j)*HH + k0;
        pw[2][jj] = W_ih + (size_t)(2*HH+j)*HH + k0;
        pw[3][jj] = W_hh + (size_t)j*HH + k0;
        pw[4][jj] = W_hh + (size_t)(HH+j)*HH + k0;
        pw[5][jj] = W_hh + (size_t)(2*HH+j)*HH + k0;
        #pragma unroll
        for (int g=0;g<6;g++) a[g][jj] = 0.f;
    }
    for (int k=0;k<KC;k+=4){
        float x0 = x2T[(k0+k+0)*BB+lane], x1 = x2T[(k0+k+1)*BB+lane];
        float x2 = x2T[(k0+k+2)*BB+lane], x3 = x2T[(k0+k+3)*BB+lane];
        float h0 = hT[(k0+k+0)*BB+lane], h1 = hT[(k0+k+1)*BB+lane];
        float h2 = hT[(k0+k+2)*BB+lane], h3 = hT[(k0+k+3)*BB+lane];
        #pragma unroll
        for (int jj=0;jj<4;jj++){
            float4 v;
            v = *(const float4*)(pw[0][jj]+k); a[0][jj] += x0*v.x + x1*v.y + x2*v.z + x3*v.w;
            v = *(const float4*)(pw[1][jj]+k); a[1][jj] += x0*v.x + x1*v.y + x2*v.z + x3*v.w;
            v = *(const float4*)(pw[2][jj]+k); a[2][jj] += x0*v.x + x1*v.y + x2*v.z + x3*v.w;
            v = *(const float4*)(pw[3][jj]+k); a[3][jj] += h0*v.x + h1*v.y + h2*v.z + h3*v.w;
            v = *(const float4*)(pw[4][jj]+k); a[4][jj] += h0*v.x + h1*v.y + h2*v.z + h3*v.w;
            v = *(const float4*)(pw[5][jj]+k); a[5][jj] += h0*v.x + h1*v.y + h2*v.z + h3*v.w;
        }
    }
    #pragma unroll
    for (int g=0;g<6;g++)
        #pragma unroll
        for (int jj=0;jj<4;jj++)
            gpart[((size_t)(kc*6+g)*HH + (j0+jj))*BB + lane] = a[g][jj];
}

// ---------- F2: reduce k-split partials, GRU gates, h_new, relu(h_new) transposed ----------
__global__ __launch_bounds__(256) void kF2(const float* __restrict__ gpart,
                                           const float* __restrict__ b_ih,
                                           const float* __restrict__ b_hh,
                                           const float* __restrict__ hT,
                                           float* __restrict__ hnew,   // (B,H) at d_out+64
                                           float* __restrict__ rhT)    // (H,B)
{
    int lane = threadIdx.x & 63, w = threadIdx.x >> 6;
    int j = blockIdx.x*4 + w;
    float g[6];
    #pragma unroll
    for (int gi=0; gi<6; gi++){
        float s = 0.f;
        #pragma unroll
        for (int kc=0;kc<KS;kc++) s += gpart[((size_t)(kc*6+gi)*HH + j)*BB + lane];
        g[gi] = s;
    }
    float r = sigm(g[0]+b_ih[j]      + g[3]+b_hh[j]);
    float z = sigm(g[1]+b_ih[HH+j]   + g[4]+b_hh[HH+j]);
    float n = tanhf(g[2]+b_ih[2*HH+j] + r*(g[5]+b_hh[2*HH+j]));
    float hold = hT[j*BB + lane];
    float hn = (1.f - z)*n + z*hold;
    hnew[(size_t)lane*HH + j] = hn;
    rhT[(size_t)j*BB + lane]  = fmaxf(hn, 0.f);
}

// ---------- G: out[b] = relu(h_new[b]) . out_W + out_b ----------
__global__ __launch_bounds__(512) void kG(const float* __restrict__ rhT,
                                          const float* __restrict__ out_W,
                                          const float* __restrict__ out_b,
                                          float* __restrict__ out)
{
    int b = threadIdx.x & 63, grp = threadIdx.x >> 6;  // 8 groups
    float p = 0.f;
    for (int j = grp*128; j < grp*128+128; j++) p += rhT[(size_t)j*BB + b]*out_W[j];
    __shared__ float red[8][64];
    red[grp][b] = p;
    __syncthreads();
    if (grp==0){
        float t = 0.f;
        #pragma unroll
        for (int q=0;q<8;q++) t += red[q][b];
        out[b] = t + out_b[0];
    }
}

extern "C" void kernel_launch(void* const* d_in, const int* in_sizes, int n_in,
                              void* d_out, int out_size, void* d_ws, size_t ws_size,
                              hipStream_t stream) {
    const float* input     = (const float*)d_in[0];
    const float* hidden    = (const float*)d_in[1];
    const float* enc       = (const float*)d_in[2];
    const int*   mask      = (const int*)  d_in[3];
    const float* attn_W    = (const float*)d_in[4];
    const float* attn_b    = (const float*)d_in[5];
    const float* combine_W = (const float*)d_in[6];
    const float* combine_b = (const float*)d_in[7];
    const float* W_ih      = (const float*)d_in[8];
    const float* W_hh      = (const float*)d_in[9];
    const float* b_ih      = (const float*)d_in[10];
    const float* b_hh      = (const float*)d_in[11];
    const float* out_W     = (const float*)d_in[12];
    const float* out_b     = (const float*)d_in[13];

    float* out  = (float*)d_out;
    float* hnew = out + 64;            // (1,B,H)
    float* attw = out + 64 + BB*HH;    // (B,S,1) — also holds raw scores between kB and kD
    float* ws   = (float*)d_ws;

    kA <<<64,  256, 0, stream>>>(hidden, input, attn_W, attn_b, ws+WS_HT, ws+WS_BASE);
    kB <<<BB*NCHUNK, 256, 0, stream>>>(enc, mask, attn_W, ws+WS_BASE, attw, ws+WS_BIG, ws+WS_PM, ws+WS_PL);
    kC <<<64,  256, 0, stream>>>(ws+WS_BIG, ws+WS_PM, ws+WS_PL, input, ws+WS_XT, ws+WS_MB, ws+WS_LB);
    kD <<<BB*SS/256, 256, 0, stream>>>(attw, ws+WS_MB, ws+WS_LB);
    kE <<<128, 256, 0, stream>>>(ws+WS_XT, combine_W, combine_b, ws+WS_X2T);
    kF1<<<256, 256, 0, stream>>>(ws+WS_X2T, ws+WS_HT, W_ih, W_hh, ws+WS_BIG);
    kF2<<<256, 256, 0, stream>>>(ws+WS_BIG, b_ih, b_hh, ws+WS_HT, hnew, ws+WS_RHT);
    kG <<<1,   512, 0, stream>>>(ws+WS_RHT, out_W, out_b, out);
}

// Round 2
// 206.789 us; speedup vs baseline: 1.6984x; 1.6984x over previous
//
#include <hip/hip_runtime.h>
#include <math.h>

#define BB 64
#define SS 2048
#define FF 1024
#define HH 1024
#define NCHUNK 16
#define CHUNK_S 128   // SS/NCHUNK
#define RPW 32        // rows per wave

// ---- workspace layout (float offsets) ----
#define WS_BASE 0                       // 64
#define WS_PL   64                      // 1024
#define WS_LB   (64+1024)               // 64
#define WS_OUTP (64+1024+64)            // 16384
#define WS_XT   (WS_OUTP+16384)         // 65536
#define WS_HT   (WS_XT+65536)           // 65536
#define WS_X2T  (WS_HT+65536)           // 65536
#define WS_BIG  (WS_X2T+65536)          // 1572864 (pacc 1048576 / epart 262144 / gpart 1572864, lifetimes disjoint)

__device__ __forceinline__ float sigm(float x){ return 1.f/(1.f + __expf(-x)); }

// ---------- A: transpose hidden -> hT[k][b], base[b] = h.w_h + input*w_i + attn_b ----------
__global__ __launch_bounds__(256) void kA(const float* __restrict__ h,
                                          const float* __restrict__ input,
                                          const float* __restrict__ attn_W,
                                          const float* __restrict__ attn_b,
                                          float* __restrict__ hT,
                                          float* __restrict__ base)
{
    int b = blockIdx.x;
    int tid = threadIdx.x;                 // 256
    const float4* h4  = (const float4*)(h + (size_t)b*HH);
    const float4* wh4 = (const float4*)(attn_W + FF);
    float4 hv = h4[tid];
    float4 wv = wh4[tid];
    int k = tid*4;
    hT[(k+0)*BB + b] = hv.x;
    hT[(k+1)*BB + b] = hv.y;
    hT[(k+2)*BB + b] = hv.z;
    hT[(k+3)*BB + b] = hv.w;
    float p = hv.x*wv.x + hv.y*wv.y + hv.z*wv.z + hv.w*wv.w;
    #pragma unroll
    for (int off=32; off; off>>=1) p += __shfl_xor(p, off);
    __shared__ float red[4];
    if ((tid&63)==0) red[tid>>6] = p;
    __syncthreads();
    if (tid==0){
        float dot = red[0]+red[1]+red[2]+red[3];
        base[b] = dot + input[b]*attn_W[FF+HH] + attn_b[0];
    }
}

// ---------- B: fused scores + softmax accumulation (no max subtraction; scores are O(1)) ----------
__global__ __launch_bounds__(256) void kB(const float* __restrict__ enc,
                                          const int*   __restrict__ mask,
                                          const float* __restrict__ attn_W,
                                          const float* __restrict__ base,
                                          float* __restrict__ scores_out,
                                          float* __restrict__ pacc,
                                          float* __restrict__ pl)
{
    const int tid  = threadIdx.x;
    const int lane = tid & 63;
    const int w    = tid >> 6;
    const int b    = blockIdx.x >> 4;
    const int c    = blockIdx.x & 15;
    const int s0   = c*CHUNK_S + w*RPW;

    const float4* we4 = (const float4*)attn_W;
    const float4 we0 = we4[lane], we1 = we4[64+lane], we2 = we4[128+lane], we3 = we4[192+lane];

    float l = 0.f;
    float4 a0 = make_float4(0,0,0,0), a1 = a0, a2 = a0, a3 = a0;
    const float bb = base[b];
    float sc_keep = 0.f;

    const float4* rowbase = (const float4*)(enc + (size_t)(b*SS + s0)*FF);
    const int* mrow = mask + b*SS + s0;

    for (int i=0;i<RPW;i++){
        const float4* row = rowbase + (size_t)i*(FF/4);
        float4 e0 = row[lane], e1 = row[64+lane], e2 = row[128+lane], e3 = row[192+lane];
        float d0 = e0.x*we0.x + e0.y*we0.y + e0.z*we0.z + e0.w*we0.w;
        float d1 = e1.x*we1.x + e1.y*we1.y + e1.z*we1.z + e1.w*we1.w;
        float d2 = e2.x*we2.x + e2.y*we2.y + e2.z*we2.z + e2.w*we2.w;
        float d3 = e3.x*we3.x + e3.y*we3.y + e3.z*we3.z + e3.w*we3.w;
        float dot = (d0+d1)+(d2+d3);
        #pragma unroll
        for (int off=32; off; off>>=1) dot += __shfl_xor(dot, off);
        float score = dot + bb;
        if (mrow[i] == 0) score = -1e10f;
        sc_keep = (lane == i) ? score : sc_keep;
        float p = __expf(score);           // masked -> exp(-1e10) == 0
        l += p;
        a0.x += p*e0.x; a0.y += p*e0.y; a0.z += p*e0.z; a0.w += p*e0.w;
        a1.x += p*e1.x; a1.y += p*e1.y; a1.z += p*e1.z; a1.w += p*e1.w;
        a2.x += p*e2.x; a2.y += p*e2.y; a2.z += p*e2.z; a2.w += p*e2.w;
        a3.x += p*e3.x; a3.y += p*e3.y; a3.z += p*e3.z; a3.w += p*e3.w;
    }
    if (lane < RPW) scores_out[b*SS + s0 + lane] = sc_keep;

    __shared__ float4 sacc[4][256];
    __shared__ float sl[4];
    if (lane==0) sl[w] = l;               // l is wave-uniform (dot was fully reduced)
    sacc[w][lane]     = a0;
    sacc[w][64+lane]  = a1;
    sacc[w][128+lane] = a2;
    sacc[w][192+lane] = a3;
    __syncthreads();
    float4 tot = sacc[0][tid];
    #pragma unroll
    for (int q=1;q<4;q++){ float4 u = sacc[q][tid]; tot.x+=u.x; tot.y+=u.y; tot.z+=u.z; tot.w+=u.w; }
    ((float4*)(pacc + (size_t)blockIdx.x*FF))[tid] = tot;
    if (tid==0) pl[blockIdx.x] = sl[0]+sl[1]+sl[2]+sl[3];
}

// ---------- C: merge chunk partials -> xT[f][b] (normalized attn_applied), invL per b ----------
__global__ __launch_bounds__(256) void kC(const float* __restrict__ pacc,
                                          const float* __restrict__ pl,
                                          float* __restrict__ xT,
                                          float* __restrict__ Lb)
{
    int b = blockIdx.x, tid = threadIdx.x;
    float L = 0.f;
    #pragma unroll
    for (int c=0;c<NCHUNK;c++) L += pl[b*NCHUNK+c];
    float invL = 1.f/L;
    #pragma unroll
    for (int q=0;q<4;q++){
        int f = q*256 + tid;
        float a = 0.f;
        #pragma unroll
        for (int c=0;c<NCHUNK;c++) a += pacc[((size_t)(b*NCHUNK+c))*FF + f];
        xT[(size_t)f*BB + b] = a*invL;
    }
    if (tid==0) Lb[b] = invL;
}

// ---------- D: raw scores -> softmax weights (in place) ----------
__global__ __launch_bounds__(256) void kD(float* __restrict__ wout,
                                          const float* __restrict__ Lb)
{
    int idx = blockIdx.x*256 + threadIdx.x;
    int b = idx >> 11;
    wout[idx] = __expf(wout[idx]) * Lb[b];
}

// ---------- E1: combine-GEMM partials, LDS-staged, k-split ----------
__global__ __launch_bounds__(512) void kE1(const float* __restrict__ xT,
                                           const float* __restrict__ cW,
                                           float* __restrict__ epart)
{
    __shared__ __align__(16) float Xl[256*64];   // 64 KB
    __shared__ __align__(16) float Wl[16*256];   // 16 KB
    int tid = threadIdx.x, lane = tid&63, w = tid>>6;
    int jb = blockIdx.x >> 2, kc = blockIdx.x & 3;
    int j0 = jb*16, k0 = kc*256;

    const float4* xs = (const float4*)(xT + (size_t)k0*BB);
    float4* xd = (float4*)Xl;
    for (int r=tid; r<4096; r+=512) xd[r] = xs[r];
    for (int idx=tid; idx<4096; idx+=512){
        int row = idx>>8, kk = idx&255;
        Wl[idx] = cW[(size_t)(j0+row)*(FF+1) + 1 + k0 + kk];
    }
    __syncthreads();

    float acc0 = 0.f, acc1 = 0.f;
    const float* w0p = Wl + (w*2+0)*256;
    const float* w1p = Wl + (w*2+1)*256;
    for (int kk=0; kk<256; kk+=4){
        float x0 = Xl[kk*64+lane], x1 = Xl[(kk+1)*64+lane];
        float x2 = Xl[(kk+2)*64+lane], x3 = Xl[(kk+3)*64+lane];
        float4 wa = *(const float4*)(w0p+kk);
        float4 wb = *(const float4*)(w1p+kk);
        acc0 += x0*wa.x + x1*wa.y + x2*wa.z + x3*wa.w;
        acc1 += x0*wb.x + x1*wb.y + x2*wb.z + x3*wb.w;
    }
    epart[((size_t)kc*HH + j0 + w*2+0)*BB + lane] = acc0;
    epart[((size_t)kc*HH + j0 + w*2+1)*BB + lane] = acc1;
}

// ---------- E2: reduce partials + input column + bias, relu -> x2T[j][b] ----------
__global__ __launch_bounds__(256) void kE2(const float* __restrict__ epart,
                                           const float* __restrict__ input,
                                           const float* __restrict__ cW,
                                           const float* __restrict__ cb,
                                           float* __restrict__ x2T)
{
    int tid = threadIdx.x, lane = tid&63, w = tid>>6;
    int j = blockIdx.x*4 + w;
    float s = 0.f;
    #pragma unroll
    for (int kc=0;kc<4;kc++) s += epart[((size_t)kc*HH + j)*BB + lane];
    s += input[lane]*cW[(size_t)j*(FF+1)] + cb[j];
    x2T[(size_t)j*BB + lane] = fmaxf(s, 0.f);
}

// ---------- F1: GRU-GEMM partials (6144 rows = [W_ih;W_hh]), LDS-staged, k-split ----------
__global__ __launch_bounds__(512) void kF1(const float* __restrict__ x2T,
                                           const float* __restrict__ hT,
                                           const float* __restrict__ W_ih,
                                           const float* __restrict__ W_hh,
                                           float* __restrict__ gpart)
{
    __shared__ __align__(16) float Xl[256*64];   // 64 KB
    __shared__ __align__(16) float Wl[32*256];   // 32 KB
    int tid = threadIdx.x, lane = tid&63, w = tid>>6;
    int rb = blockIdx.x >> 2, kc = blockIdx.x & 3;
    int r0 = rb*32, k0 = kc*256;
    bool ih = (r0 < 3*HH);
    const float* X  = ih ? x2T : hT;
    const float* Wb = ih ? (W_ih + (size_t)r0*HH) : (W_hh + (size_t)(r0-3*HH)*HH);

    const float4* xs = (const float4*)(X + (size_t)k0*BB);
    float4* xd = (float4*)Xl;
    for (int r=tid; r<4096; r+=512) xd[r] = xs[r];
    float4* wd = (float4*)Wl;
    for (int idx4=tid; idx4<2048; idx4+=512){
        int row = idx4>>6, kq = idx4&63;
        wd[idx4] = *(const float4*)(Wb + (size_t)row*HH + k0 + kq*4);
    }
    __syncthreads();

    float acc[4] = {0.f,0.f,0.f,0.f};
    const float* wp = Wl + (w*4)*256;
    for (int kk=0; kk<256; kk+=4){
        float x0 = Xl[kk*64+lane], x1 = Xl[(kk+1)*64+lane];
        float x2 = Xl[(kk+2)*64+lane], x3 = Xl[(kk+3)*64+lane];
        #pragma unroll
        for (int jj=0;jj<4;jj++){
            float4 wv = *(const float4*)(wp + jj*256 + kk);
            acc[jj] += x0*wv.x + x1*wv.y + x2*wv.z + x3*wv.w;
        }
    }
    #pragma unroll
    for (int jj=0;jj<4;jj++)
        gpart[((size_t)kc*6*HH + r0 + w*4 + jj)*BB + lane] = acc[jj];
}

// ---------- F2: reduce partials, GRU gates, h_new, partial out-projection ----------
__global__ __launch_bounds__(256) void kF2(const float* __restrict__ gpart,
                                           const float* __restrict__ b_ih,
                                           const float* __restrict__ b_hh,
                                           const float* __restrict__ hT,
                                           const float* __restrict__ out_W,
                                           float* __restrict__ hnew,
                                           float* __restrict__ outpart)
{
    int tid = threadIdx.x, lane = tid&63, w = tid>>6;
    int j = blockIdx.x*4 + w;
    float g[6];
    #pragma unroll
    for (int gi=0; gi<6; gi++){
        float s = 0.f;
        #pragma unroll
        for (int kc=0;kc<4;kc++) s += gpart[((size_t)kc*6*HH + gi*HH + j)*BB + lane];
        g[gi] = s;
    }
    float r = sigm(g[0]+b_ih[j]        + g[3]+b_hh[j]);
    float z = sigm(g[1]+b_ih[HH+j]     + g[4]+b_hh[HH+j]);
    float n = tanhf(g[2]+b_ih[2*HH+j]  + r*(g[5]+b_hh[2*HH+j]));
    float hold = hT[(size_t)j*BB + lane];
    float hn = (1.f - z)*n + z*hold;
    hnew[(size_t)lane*HH + j] = hn;
    float pv = fmaxf(hn, 0.f) * out_W[j];
    __shared__ float red[4][64];
    red[w][lane] = pv;
    __syncthreads();
    if (w==0) outpart[blockIdx.x*64 + lane] = red[0][lane]+red[1][lane]+red[2][lane]+red[3][lane];
}

// ---------- G2: final out reduction ----------
__global__ __launch_bounds__(256) void kG2(const float* __restrict__ outpart,
                                           const float* __restrict__ out_b,
                                           float* __restrict__ out)
{
    int tid = threadIdx.x, b = tid&63, q = tid>>6;
    float s = 0.f;
    for (int p=q*64; p<q*64+64; p++) s += outpart[p*64 + b];
    __shared__ float red[4][64];
    red[q][b] = s;
    __syncthreads();
    if (q==0) out[b] = red[0][b]+red[1][b]+red[2][b]+red[3][b] + out_b[0];
}

extern "C" void kernel_launch(void* const* d_in, const int* in_sizes, int n_in,
                              void* d_out, int out_size, void* d_ws, size_t ws_size,
                              hipStream_t stream) {
    const float* input     = (const float*)d_in[0];
    const float* hidden    = (const float*)d_in[1];
    const float* enc       = (const float*)d_in[2];
    const int*   mask      = (const int*)  d_in[3];
    const float* attn_W    = (const float*)d_in[4];
    const float* attn_b    = (const float*)d_in[5];
    const float* combine_W = (const float*)d_in[6];
    const float* combine_b = (const float*)d_in[7];
    const float* W_ih      = (const float*)d_in[8];
    const float* W_hh      = (const float*)d_in[9];
    const float* b_ih      = (const float*)d_in[10];
    const float* b_hh      = (const float*)d_in[11];
    const float* out_W     = (const float*)d_in[12];
    const float* out_b     = (const float*)d_in[13];

    float* out  = (float*)d_out;
    float* hnew = out + 64;            // (1,B,H)
    float* attw = out + 64 + BB*HH;    // (B,S,1) — raw scores between kB and kD
    float* ws   = (float*)d_ws;

    kA <<<64,   256, 0, stream>>>(hidden, input, attn_W, attn_b, ws+WS_HT, ws+WS_BASE);
    kB <<<BB*NCHUNK, 256, 0, stream>>>(enc, mask, attn_W, ws+WS_BASE, attw, ws+WS_BIG, ws+WS_PL);
    kC <<<64,   256, 0, stream>>>(ws+WS_BIG, ws+WS_PL, ws+WS_XT, ws+WS_LB);
    kD <<<BB*SS/256, 256, 0, stream>>>(attw, ws+WS_LB);
    kE1<<<256,  512, 0, stream>>>(ws+WS_XT, combine_W, ws+WS_BIG);
    kE2<<<256,  256, 0, stream>>>(ws+WS_BIG, input, combine_W, combine_b, ws+WS_X2T);
    kF1<<<768,  512, 0, stream>>>(ws+WS_X2T, ws+WS_HT, W_ih, W_hh, ws+WS_BIG);
    kF2<<<256,  256, 0, stream>>>(ws+WS_BIG, b_ih, b_hh, ws+WS_HT, out_W, hnew, ws+WS_OUTP);
    kG2<<<1,    256, 0, stream>>>(ws+WS_OUTP, out_b, out);
}

// Round 3
// 160.927 us; speedup vs baseline: 2.1824x; 1.2850x over previous
//
#include <hip/hip_runtime.h>
#include <math.h>

#define BB 64
#define SS 2048
#define FF 1024
#define HH 1024
#define NCHUNK 32
#define CHUNK_S 64    // SS/NCHUNK
#define RPW 16        // rows per wave (CHUNK_S/4)
#define KSPLIT 8
#define KCH 128       // HH/KSPLIT

// ---- workspace layout (float offsets) ----
#define WS_PL    0                        // 2048
#define WS_XT    2048                     // 65536
#define WS_HT    (WS_XT+65536)            // 65536
#define WS_X2T   (WS_HT+65536)            // 65536
#define WS_EPART (WS_X2T+65536)           // 8*1024*64   = 524288
#define WS_GPART (WS_EPART+524288)        // 8*6144*64   = 3145728
#define WS_PACC  (WS_GPART+3145728)       // 2048*1024   = 2097152

__device__ __forceinline__ float sigm(float x){ return 1.f/(1.f + __expf(-x)); }

// ---------- B: fused scores + softmax accumulation (base computed per-wave; no max subtraction) ----------
__global__ __launch_bounds__(256) void kB(const float* __restrict__ enc,
                                          const int*   __restrict__ mask,
                                          const float* __restrict__ attn_W,
                                          const float* __restrict__ input,
                                          const float* __restrict__ hidden,
                                          const float* __restrict__ attn_b,
                                          float* __restrict__ scores_out,
                                          float* __restrict__ pacc,
                                          float* __restrict__ pl)
{
    const int tid  = threadIdx.x;
    const int lane = tid & 63;
    const int w    = tid >> 6;
    const int b    = blockIdx.x >> 5;
    const int c    = blockIdx.x & 31;
    const int s0   = c*CHUNK_S + w*RPW;

    const float4* we4 = (const float4*)attn_W;
    const float4 we0 = we4[lane], we1 = we4[64+lane], we2 = we4[128+lane], we3 = we4[192+lane];

    // per-wave redundant base[b] = h.w_h + input*w_i + attn_b
    {
    }
    const float4* h4  = (const float4*)(hidden + (size_t)b*HH);
    const float4* wh4 = (const float4*)(attn_W + FF);
    float4 hv0 = h4[lane], hv1 = h4[64+lane], hv2 = h4[128+lane], hv3 = h4[192+lane];
    float4 wv0 = wh4[lane], wv1 = wh4[64+lane], wv2 = wh4[128+lane], wv3 = wh4[192+lane];
    float bp = hv0.x*wv0.x + hv0.y*wv0.y + hv0.z*wv0.z + hv0.w*wv0.w
             + hv1.x*wv1.x + hv1.y*wv1.y + hv1.z*wv1.z + hv1.w*wv1.w
             + hv2.x*wv2.x + hv2.y*wv2.y + hv2.z*wv2.z + hv2.w*wv2.w
             + hv3.x*wv3.x + hv3.y*wv3.y + hv3.z*wv3.z + hv3.w*wv3.w;
    #pragma unroll
    for (int off=32; off; off>>=1) bp += __shfl_xor(bp, off);
    const float bb = bp + input[b]*attn_W[FF+HH] + attn_b[0];

    float l = 0.f;
    float4 a0 = make_float4(0,0,0,0), a1 = a0, a2 = a0, a3 = a0;
    float sc_keep = 0.f;

    const float4* rowbase = (const float4*)(enc + (size_t)(b*SS + s0)*FF);
    const int* mrow = mask + b*SS + s0;

    for (int i=0;i<RPW;i+=2){
        const float4* rowA = rowbase + (size_t)i*(FF/4);
        const float4* rowB = rowA + (FF/4);
        float4 e0 = rowA[lane], e1 = rowA[64+lane], e2 = rowA[128+lane], e3 = rowA[192+lane];
        float4 f0 = rowB[lane], f1 = rowB[64+lane], f2 = rowB[128+lane], f3 = rowB[192+lane];
        int2 mk = *(const int2*)(mrow + i);

        float da = (e0.x*we0.x + e0.y*we0.y + e0.z*we0.z + e0.w*we0.w)
                 + (e1.x*we1.x + e1.y*we1.y + e1.z*we1.z + e1.w*we1.w)
                 + (e2.x*we2.x + e2.y*we2.y + e2.z*we2.z + e2.w*we2.w)
                 + (e3.x*we3.x + e3.y*we3.y + e3.z*we3.z + e3.w*we3.w);
        float db = (f0.x*we0.x + f0.y*we0.y + f0.z*we0.z + f0.w*we0.w)
                 + (f1.x*we1.x + f1.y*we1.y + f1.z*we1.z + f1.w*we1.w)
                 + (f2.x*we2.x + f2.y*we2.y + f2.z*we2.z + f2.w*we2.w)
                 + (f3.x*we3.x + f3.y*we3.y + f3.z*we3.z + f3.w*we3.w);
        #pragma unroll
        for (int off=32; off; off>>=1){ da += __shfl_xor(da, off); db += __shfl_xor(db, off); }
        float sA = da + bb, sB = db + bb;
        if (mk.x == 0) sA = -1e10f;
        if (mk.y == 0) sB = -1e10f;
        sc_keep = (lane == i)   ? sA : sc_keep;
        sc_keep = (lane == i+1) ? sB : sc_keep;
        float pA = __expf(sA), pB = __expf(sB);
        l += pA + pB;
        a0.x += pA*e0.x + pB*f0.x; a0.y += pA*e0.y + pB*f0.y; a0.z += pA*e0.z + pB*f0.z; a0.w += pA*e0.w + pB*f0.w;
        a1.x += pA*e1.x + pB*f1.x; a1.y += pA*e1.y + pB*f1.y; a1.z += pA*e1.z + pB*f1.z; a1.w += pA*e1.w + pB*f1.w;
        a2.x += pA*e2.x + pB*f2.x; a2.y += pA*e2.y + pB*f2.y; a2.z += pA*e2.z + pB*f2.z; a2.w += pA*e2.w + pB*f2.w;
        a3.x += pA*e3.x + pB*f3.x; a3.y += pA*e3.y + pB*f3.y; a3.z += pA*e3.z + pB*f3.z; a3.w += pA*e3.w + pB*f3.w;
    }
    if (lane < RPW) scores_out[b*SS + s0 + lane] = sc_keep;

    __shared__ float4 sacc[4][256];
    __shared__ float sl[4];
    if (lane==0) sl[w] = l;
    sacc[w][lane]     = a0;
    sacc[w][64+lane]  = a1;
    sacc[w][128+lane] = a2;
    sacc[w][192+lane] = a3;
    __syncthreads();
    float4 tot = sacc[0][tid];
    #pragma unroll
    for (int q=1;q<4;q++){ float4 u = sacc[q][tid]; tot.x+=u.x; tot.y+=u.y; tot.z+=u.z; tot.w+=u.w; }
    ((float4*)(pacc + (size_t)blockIdx.x*FF))[tid] = tot;
    if (tid==0) pl[blockIdx.x] = sl[0]+sl[1]+sl[2]+sl[3];
}

// ---------- C: merge partials -> xT; per-q extra duties: scores->weights, hT transpose, out init ----------
__global__ __launch_bounds__(256) void kC(const float* __restrict__ pacc,
                                          const float* __restrict__ pl,
                                          const float* __restrict__ hidden,
                                          const float* __restrict__ out_b,
                                          float* __restrict__ xT,
                                          float* __restrict__ wout,
                                          float* __restrict__ hT,
                                          float* __restrict__ out)
{
    int b = blockIdx.x >> 2, q = blockIdx.x & 3, tid = threadIdx.x;
    float L = 0.f;
    #pragma unroll
    for (int c=0;c<NCHUNK;c++) L += pl[b*NCHUNK+c];
    float invL = 1.f/L;

    int f = q*256 + tid;
    float a = 0.f;
    #pragma unroll
    for (int c=0;c<NCHUNK;c++) a += pacc[((size_t)(b*NCHUNK+c))*FF + f];
    xT[(size_t)f*BB + b] = a*invL;

    if (q == 0){
        for (int t = tid; t < SS; t += 256){
            int idx = b*SS + t;
            wout[idx] = __expf(wout[idx]) * invL;
        }
    } else if (q == 1){
        for (int k = tid; k < HH; k += 256) hT[(size_t)k*BB + b] = hidden[(size_t)b*HH + k];
    } else if (q == 2){
        if (tid == 0) out[b] = out_b[0];
    }
}

// ---------- E1: combine-GEMM partials (j-tile 16, k-chunk 128), LDS-staged ----------
__global__ __launch_bounds__(256) void kE1(const float* __restrict__ xT,
                                           const float* __restrict__ cW,
                                           float* __restrict__ epart)
{
    __shared__ __align__(16) float Xl[KCH*64];   // 32 KB
    __shared__ __align__(16) float Wl[16*KCH];   // 8 KB
    int tid = threadIdx.x, lane = tid&63, w = tid>>6;
    int jb = blockIdx.x >> 3, kc = blockIdx.x & 7;
    int j0 = jb*16, k0 = kc*KCH;

    const float4* xs = (const float4*)(xT + (size_t)k0*BB);
    float4* xd = (float4*)Xl;
    #pragma unroll
    for (int r=tid; r<KCH*16; r+=256) xd[r] = xs[r];
    for (int idx=tid; idx<16*KCH; idx+=256){
        int row = idx>>7, kk = idx&127;
        Wl[idx] = cW[(size_t)(j0+row)*(FF+1) + 1 + k0 + kk];
    }
    __syncthreads();

    float acc[4] = {0.f,0.f,0.f,0.f};
    const float* wp = Wl + (w*4)*KCH;
    for (int kk=0; kk<KCH; kk+=4){
        float x0 = Xl[kk*64+lane], x1 = Xl[(kk+1)*64+lane];
        float x2 = Xl[(kk+2)*64+lane], x3 = Xl[(kk+3)*64+lane];
        #pragma unroll
        for (int jj=0;jj<4;jj++){
            float4 wv = *(const float4*)(wp + jj*KCH + kk);
            acc[jj] += x0*wv.x + x1*wv.y + x2*wv.z + x3*wv.w;
        }
    }
    #pragma unroll
    for (int jj=0;jj<4;jj++)
        epart[((size_t)kc*HH + j0 + w*4 + jj)*BB + lane] = acc[jj];
}

// ---------- E2: reduce partials + input column + bias, relu -> x2T ----------
__global__ __launch_bounds__(256) void kE2(const float* __restrict__ epart,
                                           const float* __restrict__ input,
                                           const float* __restrict__ cW,
                                           const float* __restrict__ cb,
                                           float* __restrict__ x2T)
{
    int tid = threadIdx.x, lane = tid&63, w = tid>>6;
    int j = blockIdx.x*4 + w;
    float s = 0.f;
    #pragma unroll
    for (int kc=0;kc<KSPLIT;kc++) s += epart[((size_t)kc*HH + j)*BB + lane];
    s += input[lane]*cW[(size_t)j*(FF+1)] + cb[j];
    x2T[(size_t)j*BB + lane] = fmaxf(s, 0.f);
}

// ---------- F1: GRU-GEMM partials (6144 rows, r-tile 16, k-chunk 128), LDS-staged ----------
__global__ __launch_bounds__(256) void kF1(const float* __restrict__ x2T,
                                           const float* __restrict__ hT,
                                           const float* __restrict__ W_ih,
                                           const float* __restrict__ W_hh,
                                           float* __restrict__ gpart)
{
    __shared__ __align__(16) float Xl[KCH*64];   // 32 KB
    __shared__ __align__(16) float Wl[16*KCH];   // 8 KB
    int tid = threadIdx.x, lane = tid&63, w = tid>>6;
    int rb = blockIdx.x >> 3, kc = blockIdx.x & 7;
    int r0 = rb*16, k0 = kc*KCH;
    bool ih = (r0 < 3*HH);
    const float* X  = ih ? x2T : hT;
    const float* Wb = ih ? (W_ih + (size_t)r0*HH) : (W_hh + (size_t)(r0-3*HH)*HH);

    const float4* xs = (const float4*)(X + (size_t)k0*BB);
    float4* xd = (float4*)Xl;
    #pragma unroll
    for (int r=tid; r<KCH*16; r+=256) xd[r] = xs[r];
    float4* wd = (float4*)Wl;
    #pragma unroll
    for (int idx4=tid; idx4<16*KCH/4; idx4+=256){
        int row = idx4>>5, kq = idx4&31;
        wd[idx4] = *(const float4*)(Wb + (size_t)row*HH + k0 + kq*4);
    }
    __syncthreads();

    float acc[4] = {0.f,0.f,0.f,0.f};
    const float* wp = Wl + (w*4)*KCH;
    for (int kk=0; kk<KCH; kk+=4){
        float x0 = Xl[kk*64+lane], x1 = Xl[(kk+1)*64+lane];
        float x2 = Xl[(kk+2)*64+lane], x3 = Xl[(kk+3)*64+lane];
        #pragma unroll
        for (int jj=0;jj<4;jj++){
            float4 wv = *(const float4*)(wp + jj*KCH + kk);
            acc[jj] += x0*wv.x + x1*wv.y + x2*wv.z + x3*wv.w;
        }
    }
    #pragma unroll
    for (int jj=0;jj<4;jj++)
        gpart[((size_t)kc*6*HH + r0 + w*4 + jj)*BB + lane] = acc[jj];
}

// ---------- F2: reduce partials, GRU gates, h_new, atomic out-projection ----------
__global__ __launch_bounds__(256) void kF2(const float* __restrict__ gpart,
                                           const float* __restrict__ b_ih,
                                           const float* __restrict__ b_hh,
                                           const float* __restrict__ hT,
                                           const float* __restrict__ out_W,
                                           float* __restrict__ hnew,
                                           float* __restrict__ out)
{
    int tid = threadIdx.x, lane = tid&63, w = tid>>6;
    int j = blockIdx.x*4 + w;
    float g[6];
    #pragma unroll
    for (int gi=0; gi<6; gi++){
        int row = (gi < 3) ? (gi*HH + j) : (3*HH + (gi-3)*HH + j);
        float s = 0.f;
        #pragma unroll
        for (int kc=0;kc<KSPLIT;kc++) s += gpart[((size_t)kc*6*HH + row)*BB + lane];
        g[gi] = s;
    }
    float r = sigm(g[0]+b_ih[j]        + g[3]+b_hh[j]);
    float z = sigm(g[1]+b_ih[HH+j]     + g[4]+b_hh[HH+j]);
    float n = tanhf(g[2]+b_ih[2*HH+j]  + r*(g[5]+b_hh[2*HH+j]));
    float hold = hT[(size_t)j*BB + lane];
    float hn = (1.f - z)*n + z*hold;
    hnew[(size_t)lane*HH + j] = hn;
    float pv = fmaxf(hn, 0.f) * out_W[j];
    __shared__ float red[4][64];
    red[w][lane] = pv;
    __syncthreads();
    if (w==0) atomicAdd(out + lane, red[0][lane]+red[1][lane]+red[2][lane]+red[3][lane]);
}

extern "C" void kernel_launch(void* const* d_in, const int* in_sizes, int n_in,
                              void* d_out, int out_size, void* d_ws, size_t ws_size,
                              hipStream_t stream) {
    const float* input     = (const float*)d_in[0];
    const float* hidden    = (const float*)d_in[1];
    const float* enc       = (const float*)d_in[2];
    const int*   mask      = (const int*)  d_in[3];
    const float* attn_W    = (const float*)d_in[4];
    const float* attn_b    = (const float*)d_in[5];
    const float* combine_W = (const float*)d_in[6];
    const float* combine_b = (const float*)d_in[7];
    const float* W_ih      = (const float*)d_in[8];
    const float* W_hh      = (const float*)d_in[9];
    const float* b_ih      = (const float*)d_in[10];
    const float* b_hh      = (const float*)d_in[11];
    const float* out_W     = (const float*)d_in[12];
    const float* out_b     = (const float*)d_in[13];

    float* out  = (float*)d_out;
    float* hnew = out + 64;            // (1,B,H)
    float* attw = out + 64 + BB*HH;    // (B,S,1) — raw scores between kB and kC
    float* ws   = (float*)d_ws;

    kB <<<BB*NCHUNK, 256, 0, stream>>>(enc, mask, attn_W, input, hidden, attn_b,
                                       attw, ws+WS_PACC, ws+WS_PL);
    kC <<<256,  256, 0, stream>>>(ws+WS_PACC, ws+WS_PL, hidden, out_b,
                                  ws+WS_XT, attw, ws+WS_HT, out);
    kE1<<<512,  256, 0, stream>>>(ws+WS_XT, combine_W, ws+WS_EPART);
    kE2<<<256,  256, 0, stream>>>(ws+WS_EPART, input, combine_W, combine_b, ws+WS_X2T);
    kF1<<<3072, 256, 0, stream>>>(ws+WS_X2T, ws+WS_HT, W_ih, W_hh, ws+WS_GPART);
    kF2<<<256,  256, 0, stream>>>(ws+WS_GPART, b_ih, b_hh, ws+WS_HT, out_W, hnew, out);
}